// Round 1
// baseline (551.405 us; speedup 1.0000x reference)
//
#include <hip/hip_runtime.h>
#include <hip/hip_bf16.h>

#define B_  32
#define LK  2048
#define DM  1024
#define NH  16

typedef __attribute__((ext_vector_type(8))) short short8;
typedef __attribute__((ext_vector_type(4))) float f32x4;

__device__ __forceinline__ ushort f2bf(float f){
  union { float f; unsigned u; } v; v.f = f;
  unsigned u = v.u;
  u += 0x7fffu + ((u >> 16) & 1u);   // round-to-nearest-even
  return (ushort)(u >> 16);
}

// ---- K0a: Wk [k][n] f32  ->  wkt [n][k] bf16 (transpose + convert)
__global__ __launch_bounds__(256) void k_wkt(const float* __restrict__ Wk, ushort* __restrict__ wkt){
  __shared__ float tile[32][33];
  int n0 = blockIdx.x * 32, k0 = blockIdx.y * 32;
  int tx = threadIdx.x & 31, ty = threadIdx.x >> 5;  // ty 0..7
#pragma unroll
  for (int r = 0; r < 4; ++r)
    tile[ty + 8*r][tx] = Wk[(size_t)(k0 + ty + 8*r) * DM + n0 + tx];
  __syncthreads();
#pragma unroll
  for (int r = 0; r < 4; ++r){
    int n = ty + 8*r;
    wkt[(size_t)(n0 + n) * DM + k0 + tx] = f2bf(tile[tx][n]);
  }
}

// ---- K0b: qup[b][n] = bq[n] + query[b,:] @ Wq[:,n]
__global__ __launch_bounds__(256) void k_qup(const float* __restrict__ query, const float* __restrict__ Wq,
                                             const float* __restrict__ bq, float* __restrict__ qup){
  __shared__ float q[DM];
  int b = blockIdx.x >> 2, nc = blockIdx.x & 3;
  int t = threadIdx.x;
#pragma unroll
  for (int j = 0; j < 4; ++j) q[j*256 + t] = query[(size_t)b*DM + j*256 + t];
  __syncthreads();
  int n = nc*256 + t;
  float acc = bq[n];
#pragma unroll 8
  for (int k = 0; k < DM; ++k) acc += q[k] * Wq[(size_t)k*DM + n];
  qup[(size_t)b*DM + n] = acc;
}

// ---- K2: fused bf16 MFMA GEMM (key @ Wk) + tanh-dot epilogue -> scores[b*16+h][l]
// 512 blocks (128 key-rows each), 4 waves, 128x128 tile looped over 8 column tiles.
__global__ __launch_bounds__(256, 2) void k_gemm_scores(
    const float* __restrict__ key, const ushort* __restrict__ wkt,
    const float* __restrict__ qup, const float* __restrict__ bk,
    const float* __restrict__ wsc, float* __restrict__ scores)
{
  __shared__ char lds[65536]; // A bufs @0,16384 ; B bufs @32768,49152 ; each 128 rows x 64 k x bf16
  const int tid  = threadIdx.x;
  const int lane = tid & 63;
  const int wid  = tid >> 6;
  const int wr   = wid >> 1, wc = wid & 1;
  const int l15  = lane & 15, l16 = lane >> 4;
  const int bid  = blockIdx.x;
  const int b    = bid >> 4;
  const int l0   = (bid & 15) * 128;
  const size_t row0 = (size_t)bid * 128;

  int srow[4], sk8[4];
#pragma unroll
  for (int c = 0; c < 4; ++c){ int id = c*256 + tid; srow[c] = id >> 3; sk8[c] = id & 7; }

  float wsv[4];
#pragma unroll
  for (int ni = 0; ni < 4; ++ni) wsv[ni] = wsc[ni*16 + l15];

  const f32x4 zero4 = {0.f, 0.f, 0.f, 0.f};

  for (int ct = 0; ct < 8; ++ct){
    const int head = ct*2 + wc;
    float qb[4];
#pragma unroll
    for (int ni = 0; ni < 4; ++ni){
      int n = ct*128 + wc*64 + ni*16 + l15;
      qb[ni] = qup[(size_t)b*DM + n] + bk[n];
    }

    f32x4 acc[4][4];
#pragma unroll
    for (int mi = 0; mi < 4; ++mi)
#pragma unroll
      for (int ni = 0; ni < 4; ++ni) acc[mi][ni] = zero4;

    f32x4 ar0[4], ar1[4];
    short8 br[4];

#define LOADS(KT) do { \
  _Pragma("unroll") \
  for (int c = 0; c < 4; ++c){ \
    const float* ap = key + (row0 + (size_t)srow[c])*DM + (KT)*64 + sk8[c]*8; \
    ar0[c] = *(const f32x4*)ap; \
    ar1[c] = *(const f32x4*)(ap + 4); \
    br[c]  = *(const short8*)(wkt + (size_t)(ct*128 + srow[c])*DM + (KT)*64 + sk8[c]*8); \
  } } while(0)

#define WRITES(P) do { \
  _Pragma("unroll") \
  for (int c = 0; c < 4; ++c){ \
    union { ushort u[8]; f32x4 v; } pk; \
    _Pragma("unroll") \
    for (int j = 0; j < 4; ++j){ pk.u[j] = f2bf(ar0[c][j]); pk.u[4+j] = f2bf(ar1[c][j]); } \
    int boff = srow[c]*128 + ((sk8[c]*16) ^ ((srow[c] & 7) << 4)); \
    *(f32x4*)(lds + (P)*16384 + boff) = pk.v; \
    *(short8*)(lds + 32768 + (P)*16384 + boff) = br[c]; \
  } } while(0)

    LOADS(0); WRITES(0); __syncthreads();

    for (int kt = 0; kt < 16; ++kt){
      const int cur = kt & 1;
      if (kt < 15) LOADS(kt + 1);

      short8 af[4][2], bfr[4][2];
#pragma unroll
      for (int mi = 0; mi < 4; ++mi){
        int row = wr*64 + mi*16 + l15;
#pragma unroll
        for (int kk = 0; kk < 2; ++kk){
          int kb = kk*64 + l16*16;
          af[mi][kk] = *(const short8*)(lds + cur*16384 + row*128 + (kb ^ ((row & 7) << 4)));
        }
      }
#pragma unroll
      for (int ni = 0; ni < 4; ++ni){
        int col = wc*64 + ni*16 + l15;
#pragma unroll
        for (int kk = 0; kk < 2; ++kk){
          int kb = kk*64 + l16*16;
          bfr[ni][kk] = *(const short8*)(lds + 32768 + cur*16384 + col*128 + (kb ^ ((col & 7) << 4)));
        }
      }
#pragma unroll
      for (int kk = 0; kk < 2; ++kk)
#pragma unroll
        for (int mi = 0; mi < 4; ++mi)
#pragma unroll
          for (int ni = 0; ni < 4; ++ni)
            acc[mi][ni] = __builtin_amdgcn_mfma_f32_16x16x32_bf16(af[mi][kk], bfr[ni][kk], acc[mi][ni], 0, 0, 0);

      if (kt < 15) WRITES(cur ^ 1);
      __syncthreads();
    }

    // epilogue: scores[row, head] = sum_col tanh(acc + qup + bk) * w_score
#pragma unroll
    for (int mi = 0; mi < 4; ++mi){
      f32x4 s = zero4;
#pragma unroll
      for (int ni = 0; ni < 4; ++ni)
#pragma unroll
        for (int r = 0; r < 4; ++r)
          s[r] += tanhf(acc[mi][ni][r] + qb[ni]) * wsv[ni];
#pragma unroll
      for (int r = 0; r < 4; ++r){
        float v = s[r];
        v += __shfl_xor(v, 1);
        v += __shfl_xor(v, 2);
        v += __shfl_xor(v, 4);
        v += __shfl_xor(v, 8);
        s[r] = v;
      }
      if (l15 == 0){
        *(f32x4*)(scores + (size_t)(b*NH + head)*LK + l0 + wr*64 + mi*16 + l16*4) = s;
      }
    }
#undef LOADS
#undef WRITES
  }
}

// ---- K3: masked softmax over l -> attn (output #2)
__global__ __launch_bounds__(256) void k_softmax(const float* __restrict__ scores, const int* __restrict__ mask,
                                                 float* __restrict__ attn){
  int bh = blockIdx.x; int b = bh >> 4;
  const float* s = scores + (size_t)bh * LK;
  const int*   m = mask + (size_t)b * LK;
  float*       a = attn + (size_t)bh * LK;
  int t = threadIdx.x;
  __shared__ float red[8];

  float sv[8]; int mv[8];
  float lmax = -1e30f;
#pragma unroll
  for (int j = 0; j < 8; ++j){
    int i = j*256 + t;
    sv[j] = s[i]; mv[j] = m[i];
    if (!mv[j]) lmax = fmaxf(lmax, sv[j]);
  }
#pragma unroll
  for (int off = 32; off >= 1; off >>= 1) lmax = fmaxf(lmax, __shfl_xor(lmax, off));
  if ((t & 63) == 0) red[t >> 6] = lmax;
  __syncthreads();
  lmax = fmaxf(fmaxf(red[0], red[1]), fmaxf(red[2], red[3]));

  float ev[8]; float lsum = 0.f;
#pragma unroll
  for (int j = 0; j < 8; ++j){
    ev[j] = mv[j] ? 0.f : __expf(sv[j] - lmax);
    lsum += ev[j];
  }
#pragma unroll
  for (int off = 32; off >= 1; off >>= 1) lsum += __shfl_xor(lsum, off);
  if ((t & 63) == 0) red[4 + (t >> 6)] = lsum;
  __syncthreads();
  lsum = red[4] + red[5] + red[6] + red[7];
  float inv = 1.f / lsum;
#pragma unroll
  for (int j = 0; j < 8; ++j) a[j*256 + t] = ev[j] * inv;
}

// ---- K4: context partials: part[b,ch,c] = sum_{l in chunk} attn[b,h(c),l] * value[b,l,c]
__global__ __launch_bounds__(256) void k_ctx(const float* __restrict__ value, const float* __restrict__ attn,
                                             float* __restrict__ part){
  int b = blockIdx.x >> 4, ch = blockIdx.x & 15;
  int t = threadIdx.x;
  int c4 = t * 4;
  int head = t >> 4;
  const float* ap = attn + (size_t)(b*NH + head)*LK + ch*128;
  const float* vp = value + ((size_t)b*LK + ch*128)*DM + c4;
  f32x4 acc = {0.f, 0.f, 0.f, 0.f};
#pragma unroll 4
  for (int l = 0; l < 128; ++l){
    float av = ap[l];
    f32x4 v = *(const f32x4*)(vp + (size_t)l*DM);
#pragma unroll
    for (int j = 0; j < 4; ++j) acc[j] += av * v[j];
  }
  *(f32x4*)(part + (size_t)(b*16 + ch)*DM + c4) = acc;
}

// ---- K6: reduce partials -> context; output = context @ Wf + bf (output #1)
__global__ __launch_bounds__(256) void k_out(const float* __restrict__ part, const float* __restrict__ Wf,
                                             const float* __restrict__ bfv, float* __restrict__ out){
  __shared__ float ctx[DM];
  int b = blockIdx.x >> 2, nc = blockIdx.x & 3;
  int t = threadIdx.x;
#pragma unroll
  for (int j = 0; j < 4; ++j){
    int k = j*256 + t;
    float s = 0.f;
#pragma unroll
    for (int c = 0; c < 16; ++c) s += part[(size_t)(b*16 + c)*DM + k];
    ctx[k] = s;
  }
  __syncthreads();
  int n = nc*256 + t;
  float acc = bfv[n];
#pragma unroll 8
  for (int k = 0; k < DM; ++k) acc += ctx[k] * Wf[(size_t)k*DM + n];
  out[(size_t)b*DM + n] = acc;
}

extern "C" void kernel_launch(void* const* d_in, const int* in_sizes, int n_in,
                              void* d_out, int out_size, void* d_ws, size_t ws_size,
                              hipStream_t stream){
  (void)in_sizes; (void)n_in; (void)out_size; (void)ws_size;
  const float* key   = (const float*)d_in[0];
  const float* value = (const float*)d_in[1];
  const float* query = (const float*)d_in[2];
  const int*   mask  = (const int*)d_in[3];
  const float* Wk    = (const float*)d_in[4];
  const float* bk    = (const float*)d_in[5];
  const float* Wq    = (const float*)d_in[6];
  const float* bq    = (const float*)d_in[7];
  const float* wsc   = (const float*)d_in[8];
  // d_in[9] = b_score: softmax-invariant, unused
  const float* Wf    = (const float*)d_in[10];
  const float* bfv   = (const float*)d_in[11];

  float* out0 = (float*)d_out;
  float* attn = out0 + (size_t)B_ * DM;   // [B,H,1,Lk] region

  char* ws = (char*)d_ws;
  ushort* wkt  = (ushort*)(ws);                                    // 2 MB
  float*  qup  = (float*)(ws + (2u<<20));                          // 128 KB
  float*  scr  = (float*)(ws + (2u<<20) + (128u<<10));             // 4 MB
  float*  part = (float*)(ws + (2u<<20) + (128u<<10) + (4u<<20));  // 2 MB

  k_wkt<<<dim3(32, 32), 256, 0, stream>>>(Wk, wkt);
  k_qup<<<128, 256, 0, stream>>>(query, Wq, bq, qup);
  k_gemm_scores<<<512, 256, 0, stream>>>(key, wkt, qup, bk, wsc, scr);
  k_softmax<<<512, 256, 0, stream>>>(scr, mask, attn);
  k_ctx<<<512, 256, 0, stream>>>(value, attn, part);
  k_out<<<128, 256, 0, stream>>>(part, Wf, bfv, out0);
}

// Round 2
// 439.920 us; speedup vs baseline: 1.2534x; 1.2534x over previous
//
#include <hip/hip_runtime.h>
#include <hip/hip_bf16.h>

#define B_  32
#define LK  2048
#define DM  1024
#define NH  16

typedef __attribute__((ext_vector_type(8))) short short8;
typedef __attribute__((ext_vector_type(4))) float f32x4;

__device__ __forceinline__ ushort f2bf(float f){
  union { float f; unsigned u; } v; v.f = f;
  unsigned u = v.u;
  u += 0x7fffu + ((u >> 16) & 1u);   // round-to-nearest-even
  return (ushort)(u >> 16);
}

__device__ __forceinline__ void gll16(const void* g, void* l){
  __builtin_amdgcn_global_load_lds(
      (__attribute__((address_space(1))) void*)g,
      (__attribute__((address_space(3))) void*)l, 16, 0, 0);
}

// ---- K0a: Wk [k][n] f32  ->  wkt [n][k] bf16 (transpose + convert)
__global__ __launch_bounds__(256) void k_wkt(const float* __restrict__ Wk, ushort* __restrict__ wkt){
  __shared__ float tile[32][33];
  int n0 = blockIdx.x * 32, k0 = blockIdx.y * 32;
  int tx = threadIdx.x & 31, ty = threadIdx.x >> 5;  // ty 0..7
#pragma unroll
  for (int r = 0; r < 4; ++r)
    tile[ty + 8*r][tx] = Wk[(size_t)(k0 + ty + 8*r) * DM + n0 + tx];
  __syncthreads();
#pragma unroll
  for (int r = 0; r < 4; ++r){
    int n = ty + 8*r;
    wkt[(size_t)(n0 + n) * DM + k0 + tx] = f2bf(tile[tx][n]);
  }
}

// ---- K0b: qup[b][n] = bq[n] + query[b,:] @ Wq[:,n]
__global__ __launch_bounds__(256) void k_qup(const float* __restrict__ query, const float* __restrict__ Wq,
                                             const float* __restrict__ bq, float* __restrict__ qup){
  __shared__ float q[DM];
  int b = blockIdx.x >> 2, nc = blockIdx.x & 3;
  int t = threadIdx.x;
#pragma unroll
  for (int j = 0; j < 4; ++j) q[j*256 + t] = query[(size_t)b*DM + j*256 + t];
  __syncthreads();
  int n = nc*256 + t;
  float acc = bq[n];
#pragma unroll 8
  for (int k = 0; k < DM; ++k) acc += q[k] * Wq[(size_t)k*DM + n];
  qup[(size_t)b*DM + n] = acc;
}

// ---- K1: key f32 -> bf16 prepass (one-time convert; removes 8x re-convert from GEMM)
__global__ __launch_bounds__(256) void k_keybf(const float* __restrict__ in, ushort* __restrict__ out){
  size_t i = ((size_t)blockIdx.x * 256 + threadIdx.x) * 8;
  f32x4 a = *(const f32x4*)(in + i);
  f32x4 b = *(const f32x4*)(in + i + 4);
  union { ushort u[8]; short8 s; } pk;
#pragma unroll
  for (int j = 0; j < 4; ++j){ pk.u[j] = f2bf(a[j]); pk.u[4+j] = f2bf(b[j]); }
  *(short8*)(out + i) = pk.s;
}

// ---- K2 fast: m97-structure MFMA GEMM. 4096 blocks = 512 row-panels x 8 col-tiles.
// 128x128 tile, BK=64, single 32KB LDS buffer, global_load_lds width 16, 2 barriers/K-step.
// Epilogue: tanh(acc+q+bk).w_score 16-lane reduce -> scores (b_score is softmax-invariant, skipped).
__global__ __launch_bounds__(256, 3) void k_gemm_fast(
    const ushort* __restrict__ keybf, const ushort* __restrict__ wkt,
    const float* __restrict__ qup, const float* __restrict__ bk,
    const float* __restrict__ wsc, float* __restrict__ scores)
{
  __shared__ ushort ldsA[128*64];
  __shared__ ushort ldsB[128*64];
  const int tid  = threadIdx.x;
  const int lane = tid & 63;
  const int wid  = tid >> 6;
  const int wr   = wid >> 1, wc = wid & 1;
  const int l15  = lane & 15, l16 = lane >> 4;
  const int bid  = blockIdx.x;
  const int ct   = bid >> 9;          // 0..7 column tile (consecutive bids share B panel)
  const int rb   = bid & 511;         // row panel
  const size_t row0 = (size_t)rb * 128;
  const int b    = rb >> 4;
  const int l0   = (rb & 15) * 128;

  // staging geometry: wave wid stages rows [wid*32, wid*32+32), call c covers 8 rows
  const int srow  = wid*32 + (lane >> 3);
  const int scol8 = (lane & 7) * 8;
  const ushort* abase = keybf + (row0 + (size_t)srow) * DM + scol8;
  const ushort* bbase = wkt + (size_t)(ct*128 + srow) * DM + scol8;
  char* lab = (char*)ldsA + wid*4096;
  char* lbb = (char*)ldsB + wid*4096;

  float qb[4], wsv[4];
#pragma unroll
  for (int ni = 0; ni < 4; ++ni){
    int n = ct*128 + wc*64 + ni*16 + l15;
    qb[ni]  = qup[(size_t)b*DM + n] + bk[n];
    wsv[ni] = wsc[ni*16 + l15];
  }

  const f32x4 zero4 = {0.f, 0.f, 0.f, 0.f};
  f32x4 acc[4][4];
#pragma unroll
  for (int mi = 0; mi < 4; ++mi)
#pragma unroll
    for (int ni = 0; ni < 4; ++ni) acc[mi][ni] = zero4;

  for (int kt = 0; kt < 16; ++kt){
#pragma unroll
    for (int c = 0; c < 4; ++c){
      gll16(abase + kt*64 + c*8*DM, lab + c*1024);
      gll16(bbase + kt*64 + c*8*DM, lbb + c*1024);
    }
    __syncthreads();   // drains vmcnt -> LDS tiles ready

    short8 af[4][2], bfr[4][2];
#pragma unroll
    for (int mi = 0; mi < 4; ++mi){
      int row = wr*64 + mi*16 + l15;
      af[mi][0] = *(const short8*)((const char*)ldsA + row*128 + l16*16);
      af[mi][1] = *(const short8*)((const char*)ldsA + row*128 + 64 + l16*16);
    }
#pragma unroll
    for (int ni = 0; ni < 4; ++ni){
      int col = wc*64 + ni*16 + l15;
      bfr[ni][0] = *(const short8*)((const char*)ldsB + col*128 + l16*16);
      bfr[ni][1] = *(const short8*)((const char*)ldsB + col*128 + 64 + l16*16);
    }
#pragma unroll
    for (int kk = 0; kk < 2; ++kk)
#pragma unroll
      for (int mi = 0; mi < 4; ++mi)
#pragma unroll
        for (int ni = 0; ni < 4; ++ni)
          acc[mi][ni] = __builtin_amdgcn_mfma_f32_16x16x32_bf16(af[mi][kk], bfr[ni][kk], acc[mi][ni], 0, 0, 0);

    __syncthreads();   // before overwriting the single buffer
  }

#pragma unroll
  for (int mi = 0; mi < 4; ++mi){
    f32x4 s = zero4;
#pragma unroll
    for (int ni = 0; ni < 4; ++ni)
#pragma unroll
      for (int r = 0; r < 4; ++r)
        s[r] += tanhf(acc[mi][ni][r] + qb[ni]) * wsv[ni];
#pragma unroll
    for (int r = 0; r < 4; ++r){
      float v = s[r];
      v += __shfl_xor(v, 1);
      v += __shfl_xor(v, 2);
      v += __shfl_xor(v, 4);
      v += __shfl_xor(v, 8);
      s[r] = v;
    }
    if (l15 == 0)
      *(f32x4*)(scores + (size_t)(b*NH + ct*2 + wc)*LK + l0 + wr*64 + mi*16 + l16*4) = s;
  }
}

// ---- K2 fallback (round-1 kernel, used only if ws too small for keybf)
__global__ __launch_bounds__(256, 2) void k_gemm_scores(
    const float* __restrict__ key, const ushort* __restrict__ wkt,
    const float* __restrict__ qup, const float* __restrict__ bk,
    const float* __restrict__ wsc, float* __restrict__ scores)
{
  __shared__ char lds[65536];
  const int tid  = threadIdx.x;
  const int lane = tid & 63;
  const int wid  = tid >> 6;
  const int wr   = wid >> 1, wc = wid & 1;
  const int l15  = lane & 15, l16 = lane >> 4;
  const int bid  = blockIdx.x;
  const int b    = bid >> 4;
  const int l0   = (bid & 15) * 128;
  const size_t row0 = (size_t)bid * 128;

  int srow[4], sk8[4];
#pragma unroll
  for (int c = 0; c < 4; ++c){ int id = c*256 + tid; srow[c] = id >> 3; sk8[c] = id & 7; }

  float wsv[4];
#pragma unroll
  for (int ni = 0; ni < 4; ++ni) wsv[ni] = wsc[ni*16 + l15];

  const f32x4 zero4 = {0.f, 0.f, 0.f, 0.f};

  for (int ct = 0; ct < 8; ++ct){
    const int head = ct*2 + wc;
    float qb[4];
#pragma unroll
    for (int ni = 0; ni < 4; ++ni){
      int n = ct*128 + wc*64 + ni*16 + l15;
      qb[ni] = qup[(size_t)b*DM + n] + bk[n];
    }

    f32x4 acc[4][4];
#pragma unroll
    for (int mi = 0; mi < 4; ++mi)
#pragma unroll
      for (int ni = 0; ni < 4; ++ni) acc[mi][ni] = zero4;

    f32x4 ar0[4], ar1[4];
    short8 br[4];

#define LOADS(KT) do { \
  _Pragma("unroll") \
  for (int c = 0; c < 4; ++c){ \
    const float* ap = key + (row0 + (size_t)srow[c])*DM + (KT)*64 + sk8[c]*8; \
    ar0[c] = *(const f32x4*)ap; \
    ar1[c] = *(const f32x4*)(ap + 4); \
    br[c]  = *(const short8*)(wkt + (size_t)(ct*128 + srow[c])*DM + (KT)*64 + sk8[c]*8); \
  } } while(0)

#define WRITES(P) do { \
  _Pragma("unroll") \
  for (int c = 0; c < 4; ++c){ \
    union { ushort u[8]; f32x4 v; } pk; \
    _Pragma("unroll") \
    for (int j = 0; j < 4; ++j){ pk.u[j] = f2bf(ar0[c][j]); pk.u[4+j] = f2bf(ar1[c][j]); } \
    int boff = srow[c]*128 + ((sk8[c]*16) ^ ((srow[c] & 7) << 4)); \
    *(f32x4*)(lds + (P)*16384 + boff) = pk.v; \
    *(short8*)(lds + 32768 + (P)*16384 + boff) = br[c]; \
  } } while(0)

    LOADS(0); WRITES(0); __syncthreads();

    for (int kt = 0; kt < 16; ++kt){
      const int cur = kt & 1;
      if (kt < 15) LOADS(kt + 1);

      short8 af[4][2], bfr[4][2];
#pragma unroll
      for (int mi = 0; mi < 4; ++mi){
        int row = wr*64 + mi*16 + l15;
#pragma unroll
        for (int kk = 0; kk < 2; ++kk){
          int kb = kk*64 + l16*16;
          af[mi][kk] = *(const short8*)(lds + cur*16384 + row*128 + (kb ^ ((row & 7) << 4)));
        }
      }
#pragma unroll
      for (int ni = 0; ni < 4; ++ni){
        int col = wc*64 + ni*16 + l15;
#pragma unroll
        for (int kk = 0; kk < 2; ++kk){
          int kb = kk*64 + l16*16;
          bfr[ni][kk] = *(const short8*)(lds + 32768 + cur*16384 + col*128 + (kb ^ ((col & 7) << 4)));
        }
      }
#pragma unroll
      for (int kk = 0; kk < 2; ++kk)
#pragma unroll
        for (int mi = 0; mi < 4; ++mi)
#pragma unroll
          for (int ni = 0; ni < 4; ++ni)
            acc[mi][ni] = __builtin_amdgcn_mfma_f32_16x16x32_bf16(af[mi][kk], bfr[ni][kk], acc[mi][ni], 0, 0, 0);

      if (kt < 15) WRITES(cur ^ 1);
      __syncthreads();
    }

#pragma unroll
    for (int mi = 0; mi < 4; ++mi){
      f32x4 s = zero4;
#pragma unroll
      for (int ni = 0; ni < 4; ++ni)
#pragma unroll
        for (int r = 0; r < 4; ++r)
          s[r] += tanhf(acc[mi][ni][r] + qb[ni]) * wsv[ni];
#pragma unroll
      for (int r = 0; r < 4; ++r){
        float v = s[r];
        v += __shfl_xor(v, 1);
        v += __shfl_xor(v, 2);
        v += __shfl_xor(v, 4);
        v += __shfl_xor(v, 8);
        s[r] = v;
      }
      if (l15 == 0){
        *(f32x4*)(scores + (size_t)(b*NH + head)*LK + l0 + wr*64 + mi*16 + l16*4) = s;
      }
    }
#undef LOADS
#undef WRITES
  }
}

// ---- K3: masked softmax over l -> attn (output #2)
__global__ __launch_bounds__(256) void k_softmax(const float* __restrict__ scores, const int* __restrict__ mask,
                                                 float* __restrict__ attn){
  int bh = blockIdx.x; int b = bh >> 4;
  const float* s = scores + (size_t)bh * LK;
  const int*   m = mask + (size_t)b * LK;
  float*       a = attn + (size_t)bh * LK;
  int t = threadIdx.x;
  __shared__ float red[8];

  float sv[8]; int mv[8];
  float lmax = -1e30f;
#pragma unroll
  for (int j = 0; j < 8; ++j){
    int i = j*256 + t;
    sv[j] = s[i]; mv[j] = m[i];
    if (!mv[j]) lmax = fmaxf(lmax, sv[j]);
  }
#pragma unroll
  for (int off = 32; off >= 1; off >>= 1) lmax = fmaxf(lmax, __shfl_xor(lmax, off));
  if ((t & 63) == 0) red[t >> 6] = lmax;
  __syncthreads();
  lmax = fmaxf(fmaxf(red[0], red[1]), fmaxf(red[2], red[3]));

  float ev[8]; float lsum = 0.f;
#pragma unroll
  for (int j = 0; j < 8; ++j){
    ev[j] = mv[j] ? 0.f : __expf(sv[j] - lmax);
    lsum += ev[j];
  }
#pragma unroll
  for (int off = 32; off >= 1; off >>= 1) lsum += __shfl_xor(lsum, off);
  if ((t & 63) == 0) red[4 + (t >> 6)] = lsum;
  __syncthreads();
  lsum = red[4] + red[5] + red[6] + red[7];
  float inv = 1.f / lsum;
#pragma unroll
  for (int j = 0; j < 8; ++j) a[j*256 + t] = ev[j] * inv;
}

// ---- K4: context partials: part[b,ch,c] = sum_{l in chunk} attn[b,h(c),l] * value[b,l,c]
__global__ __launch_bounds__(256) void k_ctx(const float* __restrict__ value, const float* __restrict__ attn,
                                             float* __restrict__ part){
  int b = blockIdx.x >> 4, ch = blockIdx.x & 15;
  int t = threadIdx.x;
  int c4 = t * 4;
  int head = t >> 4;
  const float* ap = attn + (size_t)(b*NH + head)*LK + ch*128;
  const float* vp = value + ((size_t)b*LK + ch*128)*DM + c4;
  f32x4 acc = {0.f, 0.f, 0.f, 0.f};
#pragma unroll 4
  for (int l = 0; l < 128; ++l){
    float av = ap[l];
    f32x4 v = *(const f32x4*)(vp + (size_t)l*DM);
#pragma unroll
    for (int j = 0; j < 4; ++j) acc[j] += av * v[j];
  }
  *(f32x4*)(part + (size_t)(b*16 + ch)*DM + c4) = acc;
}

// ---- K6: reduce partials -> context; output = context @ Wf + bf (output #1)
__global__ __launch_bounds__(256) void k_out(const float* __restrict__ part, const float* __restrict__ Wf,
                                             const float* __restrict__ bfv, float* __restrict__ out){
  __shared__ float ctx[DM];
  int b = blockIdx.x >> 2, nc = blockIdx.x & 3;
  int t = threadIdx.x;
#pragma unroll
  for (int j = 0; j < 4; ++j){
    int k = j*256 + t;
    float s = 0.f;
#pragma unroll
    for (int c = 0; c < 16; ++c) s += part[(size_t)(b*16 + c)*DM + k];
    ctx[k] = s;
  }
  __syncthreads();
  int n = nc*256 + t;
  float acc = bfv[n];
#pragma unroll 8
  for (int k = 0; k < DM; ++k) acc += ctx[k] * Wf[(size_t)k*DM + n];
  out[(size_t)b*DM + n] = acc;
}

extern "C" void kernel_launch(void* const* d_in, const int* in_sizes, int n_in,
                              void* d_out, int out_size, void* d_ws, size_t ws_size,
                              hipStream_t stream){
  (void)in_sizes; (void)n_in; (void)out_size;
  const float* key   = (const float*)d_in[0];
  const float* value = (const float*)d_in[1];
  const float* query = (const float*)d_in[2];
  const int*   mask  = (const int*)d_in[3];
  const float* Wk    = (const float*)d_in[4];
  const float* bk    = (const float*)d_in[5];
  const float* Wq    = (const float*)d_in[6];
  const float* bq    = (const float*)d_in[7];
  const float* wsc   = (const float*)d_in[8];
  // d_in[9] = b_score: softmax-invariant, unused
  const float* Wf    = (const float*)d_in[10];
  const float* bfv   = (const float*)d_in[11];

  float* out0 = (float*)d_out;
  float* attn = out0 + (size_t)B_ * DM;   // [B,H,1,Lk] region

  char* ws = (char*)d_ws;
  ushort* wkt  = (ushort*)(ws);                                    // 2 MB
  float*  qup  = (float*)(ws + (2u<<20));                          // 128 KB
  float*  scr  = (float*)(ws + (2u<<20) + (128u<<10));             // 4 MB
  float*  part = (float*)(ws + (2u<<20) + (128u<<10) + (4u<<20));  // 2 MB
  const size_t base = (2u<<20) + (128u<<10) + (4u<<20) + (2u<<20); // 8.125 MB
  ushort* keybf = (ushort*)(ws + base);                            // 128 MB (fast path)
  const bool fast = ws_size >= base + ((size_t)B_*LK*DM*sizeof(ushort));

  k_wkt<<<dim3(32, 32), 256, 0, stream>>>(Wk, wkt);
  k_qup<<<128, 256, 0, stream>>>(query, Wq, bq, qup);
  if (fast){
    k_keybf<<<32768, 256, 0, stream>>>(key, keybf);
    k_gemm_fast<<<4096, 256, 0, stream>>>(keybf, wkt, qup, bk, wsc, scr);
  } else {
    k_gemm_scores<<<512, 256, 0, stream>>>(key, wkt, qup, bk, wsc, scr);
  }
  k_softmax<<<512, 256, 0, stream>>>(scr, mask, attn);
  k_ctx<<<512, 256, 0, stream>>>(value, attn, part);
  k_out<<<128, 256, 0, stream>>>(part, Wf, bfv, out0);
}

// Round 3
// 435.976 us; speedup vs baseline: 1.2648x; 1.0090x over previous
//
#include <hip/hip_runtime.h>
#include <hip/hip_bf16.h>

#define B_  32
#define LK  2048
#define DM  1024
#define NH  16

typedef __attribute__((ext_vector_type(8))) short short8;
typedef __attribute__((ext_vector_type(4))) float f32x4;

__device__ __forceinline__ ushort f2bf(float f){
  union { float f; unsigned u; } v; v.f = f;
  unsigned u = v.u;
  u += 0x7fffu + ((u >> 16) & 1u);   // round-to-nearest-even
  return (ushort)(u >> 16);
}

__device__ __forceinline__ void gll16(const void* g, void* l){
  __builtin_amdgcn_global_load_lds(
      (__attribute__((address_space(1))) void*)g,
      (__attribute__((address_space(3))) void*)l, 16, 0, 0);
}

#define C2LOG2E 2.8853900817779268f  /* 2*log2(e) */

// ---- K0a: Wk [k][n] f32  ->  wkt [n][k] bf16 (transpose + convert)
__global__ __launch_bounds__(256) void k_wkt(const float* __restrict__ Wk, ushort* __restrict__ wkt){
  __shared__ float tile[32][33];
  int n0 = blockIdx.x * 32, k0 = blockIdx.y * 32;
  int tx = threadIdx.x & 31, ty = threadIdx.x >> 5;  // ty 0..7
#pragma unroll
  for (int r = 0; r < 4; ++r)
    tile[ty + 8*r][tx] = Wk[(size_t)(k0 + ty + 8*r) * DM + n0 + tx];
  __syncthreads();
#pragma unroll
  for (int r = 0; r < 4; ++r){
    int n = ty + 8*r;
    wkt[(size_t)(n0 + n) * DM + k0 + tx] = f2bf(tile[tx][n]);
  }
}

// ---- K0b: qup[b][n] = bq[n] + query[b,:] @ Wq[:,n]
__global__ __launch_bounds__(256) void k_qup(const float* __restrict__ query, const float* __restrict__ Wq,
                                             const float* __restrict__ bq, float* __restrict__ qup){
  __shared__ float q[DM];
  int b = blockIdx.x >> 2, nc = blockIdx.x & 3;
  int t = threadIdx.x;
#pragma unroll
  for (int j = 0; j < 4; ++j) q[j*256 + t] = query[(size_t)b*DM + j*256 + t];
  __syncthreads();
  int n = nc*256 + t;
  float acc = bq[n];
#pragma unroll 8
  for (int k = 0; k < DM; ++k) acc += q[k] * Wq[(size_t)k*DM + n];
  qup[(size_t)b*DM + n] = acc;
}

// ---- K1: key f32 -> bf16 prepass
__global__ __launch_bounds__(256) void k_keybf(const float* __restrict__ in, ushort* __restrict__ out){
  size_t i = ((size_t)blockIdx.x * 256 + threadIdx.x) * 8;
  f32x4 a = *(const f32x4*)(in + i);
  f32x4 b = *(const f32x4*)(in + i + 4);
  union { ushort u[8]; short8 s; } pk;
#pragma unroll
  for (int j = 0; j < 4; ++j){ pk.u[j] = f2bf(a[j]); pk.u[4+j] = f2bf(b[j]); }
  *(short8*)(out + i) = pk.s;
}

// ---- K2 fast: m97-structure MFMA GEMM. 4096 blocks = 512 row-panels x 8 col-tiles (ct fast).
// 128x128 tile, BK=64, single 32KB LDS buffer, global_load_lds width 16, 2 barriers/K-step.
// Epilogue uses native-exp tanh:  w*tanh(x) = w - 2w * rcp(exp2(C2LOG2E*x)+1).
__global__ __launch_bounds__(256, 5) void k_gemm_fast(
    const ushort* __restrict__ keybf, const ushort* __restrict__ wkt,
    const float* __restrict__ qup, const float* __restrict__ bk,
    const float* __restrict__ wsc, float* __restrict__ scores)
{
  __shared__ ushort ldsA[128*64];
  __shared__ ushort ldsB[128*64];
  const int tid  = threadIdx.x;
  const int lane = tid & 63;
  const int wid  = tid >> 6;
  const int wr   = wid >> 1, wc = wid & 1;
  const int l15  = lane & 15, l16 = lane >> 4;
  const int bid  = blockIdx.x;
  const int ct   = bid & 7;           // column tile FAST -> 8 siblings share keybf panel (L3 reuse)
  const int rb   = bid >> 3;          // row panel
  const size_t row0 = (size_t)rb * 128;
  const int b    = rb >> 4;
  const int l0   = (rb & 15) * 128;

  // staging geometry: wave wid stages rows [wid*32, wid*32+32), call c covers 8 rows
  const int srow  = wid*32 + (lane >> 3);
  const int scol8 = (lane & 7) * 8;
  const ushort* abase = keybf + (row0 + (size_t)srow) * DM + scol8;
  const ushort* bbase = wkt + (size_t)(ct*128 + srow) * DM + scol8;
  char* lab = (char*)ldsA + wid*4096;
  char* lbb = (char*)ldsB + wid*4096;

  float qbc[4], wm2[4], wsum = 0.f;
#pragma unroll
  for (int ni = 0; ni < 4; ++ni){
    int n = ct*128 + wc*64 + ni*16 + l15;
    float w = wsc[ni*16 + l15];
    qbc[ni] = (qup[(size_t)b*DM + n] + bk[n]) * C2LOG2E;
    wm2[ni] = -2.f * w;
    wsum   += w;
  }

  const f32x4 zero4 = {0.f, 0.f, 0.f, 0.f};
  f32x4 acc[4][4];
#pragma unroll
  for (int mi = 0; mi < 4; ++mi)
#pragma unroll
    for (int ni = 0; ni < 4; ++ni) acc[mi][ni] = zero4;

  for (int kt = 0; kt < 16; ++kt){
#pragma unroll
    for (int c = 0; c < 4; ++c){
      gll16(abase + kt*64 + c*8*DM, lab + c*1024);
      gll16(bbase + kt*64 + c*8*DM, lbb + c*1024);
    }
    __syncthreads();   // drains vmcnt -> LDS tiles ready

    short8 af[4][2], bfr[4][2];
#pragma unroll
    for (int mi = 0; mi < 4; ++mi){
      int row = wr*64 + mi*16 + l15;
      af[mi][0] = *(const short8*)((const char*)ldsA + row*128 + l16*16);
      af[mi][1] = *(const short8*)((const char*)ldsA + row*128 + 64 + l16*16);
    }
#pragma unroll
    for (int ni = 0; ni < 4; ++ni){
      int col = wc*64 + ni*16 + l15;
      bfr[ni][0] = *(const short8*)((const char*)ldsB + col*128 + l16*16);
      bfr[ni][1] = *(const short8*)((const char*)ldsB + col*128 + 64 + l16*16);
    }
#pragma unroll
    for (int kk = 0; kk < 2; ++kk)
#pragma unroll
      for (int mi = 0; mi < 4; ++mi)
#pragma unroll
        for (int ni = 0; ni < 4; ++ni)
          acc[mi][ni] = __builtin_amdgcn_mfma_f32_16x16x32_bf16(af[mi][kk], bfr[ni][kk], acc[mi][ni], 0, 0, 0);

    __syncthreads();   // before overwriting the single buffer
  }

  // epilogue: scores[row,head] = sum_col w*tanh(acc + q + bk); 16-lane shfl reduce
#pragma unroll
  for (int mi = 0; mi < 4; ++mi){
    f32x4 s = {wsum, wsum, wsum, wsum};
#pragma unroll
    for (int ni = 0; ni < 4; ++ni)
#pragma unroll
      for (int r = 0; r < 4; ++r){
        float a  = fmaf(acc[mi][ni][r], C2LOG2E, qbc[ni]);
        float e  = __builtin_amdgcn_exp2f(a);
        float rc = __builtin_amdgcn_rcpf(e + 1.f);
        s[r] = fmaf(wm2[ni], rc, s[r]);
      }
#pragma unroll
    for (int r = 0; r < 4; ++r){
      float v = s[r];
      v += __shfl_xor(v, 1);
      v += __shfl_xor(v, 2);
      v += __shfl_xor(v, 4);
      v += __shfl_xor(v, 8);
      s[r] = v;
    }
    if (l15 == 0)
      *(f32x4*)(scores + (size_t)(b*NH + ct*2 + wc)*LK + l0 + wr*64 + mi*16 + l16*4) = s;
  }
}

// ---- K2 fallback (only if ws too small for keybf)
__global__ __launch_bounds__(256, 2) void k_gemm_scores(
    const float* __restrict__ key, const ushort* __restrict__ wkt,
    const float* __restrict__ qup, const float* __restrict__ bk,
    const float* __restrict__ wsc, float* __restrict__ scores)
{
  __shared__ char lds[65536];
  const int tid  = threadIdx.x;
  const int lane = tid & 63;
  const int wid  = tid >> 6;
  const int wr   = wid >> 1, wc = wid & 1;
  const int l15  = lane & 15, l16 = lane >> 4;
  const int bid  = blockIdx.x;
  const int b    = bid >> 4;
  const int l0   = (bid & 15) * 128;
  const size_t row0 = (size_t)bid * 128;

  int srow[4], sk8[4];
#pragma unroll
  for (int c = 0; c < 4; ++c){ int id = c*256 + tid; srow[c] = id >> 3; sk8[c] = id & 7; }

  float wsv[4];
#pragma unroll
  for (int ni = 0; ni < 4; ++ni) wsv[ni] = wsc[ni*16 + l15];

  const f32x4 zero4 = {0.f, 0.f, 0.f, 0.f};

  for (int ct = 0; ct < 8; ++ct){
    const int head = ct*2 + wc;
    float qbc[4];
#pragma unroll
    for (int ni = 0; ni < 4; ++ni){
      int n = ct*128 + wc*64 + ni*16 + l15;
      qbc[ni] = (qup[(size_t)b*DM + n] + bk[n]) * C2LOG2E;
    }

    f32x4 acc[4][4];
#pragma unroll
    for (int mi = 0; mi < 4; ++mi)
#pragma unroll
      for (int ni = 0; ni < 4; ++ni) acc[mi][ni] = zero4;

    f32x4 ar0[4], ar1[4];
    short8 br[4];

#define LOADS(KT) do { \
  _Pragma("unroll") \
  for (int c = 0; c < 4; ++c){ \
    const float* ap = key + (row0 + (size_t)srow[c])*DM + (KT)*64 + sk8[c]*8; \
    ar0[c] = *(const f32x4*)ap; \
    ar1[c] = *(const f32x4*)(ap + 4); \
    br[c]  = *(const short8*)(wkt + (size_t)(ct*128 + srow[c])*DM + (KT)*64 + sk8[c]*8); \
  } } while(0)

#define WRITES(P) do { \
  _Pragma("unroll") \
  for (int c = 0; c < 4; ++c){ \
    union { ushort u[8]; f32x4 v; } pk; \
    _Pragma("unroll") \
    for (int j = 0; j < 4; ++j){ pk.u[j] = f2bf(ar0[c][j]); pk.u[4+j] = f2bf(ar1[c][j]); } \
    int boff = srow[c]*128 + ((sk8[c]*16) ^ ((srow[c] & 7) << 4)); \
    *(f32x4*)(lds + (P)*16384 + boff) = pk.v; \
    *(short8*)(lds + 32768 + (P)*16384 + boff) = br[c]; \
  } } while(0)

    LOADS(0); WRITES(0); __syncthreads();

    for (int kt = 0; kt < 16; ++kt){
      const int cur = kt & 1;
      if (kt < 15) LOADS(kt + 1);

      short8 af[4][2], bfr[4][2];
#pragma unroll
      for (int mi = 0; mi < 4; ++mi){
        int row = wr*64 + mi*16 + l15;
#pragma unroll
        for (int kk = 0; kk < 2; ++kk){
          int kb = kk*64 + l16*16;
          af[mi][kk] = *(const short8*)(lds + cur*16384 + row*128 + (kb ^ ((row & 7) << 4)));
        }
      }
#pragma unroll
      for (int ni = 0; ni < 4; ++ni){
        int col = wc*64 + ni*16 + l15;
#pragma unroll
        for (int kk = 0; kk < 2; ++kk){
          int kb = kk*64 + l16*16;
          bfr[ni][kk] = *(const short8*)(lds + 32768 + cur*16384 + col*128 + (kb ^ ((col & 7) << 4)));
        }
      }
#pragma unroll
      for (int kk = 0; kk < 2; ++kk)
#pragma unroll
        for (int mi = 0; mi < 4; ++mi)
#pragma unroll
          for (int ni = 0; ni < 4; ++ni)
            acc[mi][ni] = __builtin_amdgcn_mfma_f32_16x16x32_bf16(af[mi][kk], bfr[ni][kk], acc[mi][ni], 0, 0, 0);

      if (kt < 15) WRITES(cur ^ 1);
      __syncthreads();
    }

#pragma unroll
    for (int mi = 0; mi < 4; ++mi){
      f32x4 s = zero4;
#pragma unroll
      for (int ni = 0; ni < 4; ++ni)
#pragma unroll
        for (int r = 0; r < 4; ++r){
          float a  = fmaf(acc[mi][ni][r], C2LOG2E, qbc[ni]);
          float e  = __builtin_amdgcn_exp2f(a);
          float rc = __builtin_amdgcn_rcpf(e + 1.f);
          s[r] += wsv[ni] * fmaf(-2.f, rc, 1.f);
        }
#pragma unroll
      for (int r = 0; r < 4; ++r){
        float v = s[r];
        v += __shfl_xor(v, 1);
        v += __shfl_xor(v, 2);
        v += __shfl_xor(v, 4);
        v += __shfl_xor(v, 8);
        s[r] = v;
      }
      if (l15 == 0){
        *(f32x4*)(scores + (size_t)(b*NH + head)*LK + l0 + wr*64 + mi*16 + l16*4) = s;
      }
    }
#undef LOADS
#undef WRITES
  }
}

// ---- K3: masked softmax over l -> attn (output #2)
__global__ __launch_bounds__(256) void k_softmax(const float* __restrict__ scores, const int* __restrict__ mask,
                                                 float* __restrict__ attn){
  int bh = blockIdx.x; int b = bh >> 4;
  const float* s = scores + (size_t)bh * LK;
  const int*   m = mask + (size_t)b * LK;
  float*       a = attn + (size_t)bh * LK;
  int t = threadIdx.x;
  __shared__ float red[8];

  float sv[8]; int mv[8];
  float lmax = -1e30f;
#pragma unroll
  for (int j = 0; j < 8; ++j){
    int i = j*256 + t;
    sv[j] = s[i]; mv[j] = m[i];
    if (!mv[j]) lmax = fmaxf(lmax, sv[j]);
  }
#pragma unroll
  for (int off = 32; off >= 1; off >>= 1) lmax = fmaxf(lmax, __shfl_xor(lmax, off));
  if ((t & 63) == 0) red[t >> 6] = lmax;
  __syncthreads();
  lmax = fmaxf(fmaxf(red[0], red[1]), fmaxf(red[2], red[3]));

  float ev[8]; float lsum = 0.f;
#pragma unroll
  for (int j = 0; j < 8; ++j){
    ev[j] = mv[j] ? 0.f : __expf(sv[j] - lmax);
    lsum += ev[j];
  }
#pragma unroll
  for (int off = 32; off >= 1; off >>= 1) lsum += __shfl_xor(lsum, off);
  if ((t & 63) == 0) red[4 + (t >> 6)] = lsum;
  __syncthreads();
  lsum = red[4] + red[5] + red[6] + red[7];
  float inv = 1.f / lsum;
#pragma unroll
  for (int j = 0; j < 8; ++j) a[j*256 + t] = ev[j] * inv;
}

// ---- K4: context partials
__global__ __launch_bounds__(256) void k_ctx(const float* __restrict__ value, const float* __restrict__ attn,
                                             float* __restrict__ part){
  int b = blockIdx.x >> 4, ch = blockIdx.x & 15;
  int t = threadIdx.x;
  int c4 = t * 4;
  int head = t >> 4;
  const float* ap = attn + (size_t)(b*NH + head)*LK + ch*128;
  const float* vp = value + ((size_t)b*LK + ch*128)*DM + c4;
  f32x4 acc = {0.f, 0.f, 0.f, 0.f};
#pragma unroll 4
  for (int l = 0; l < 128; ++l){
    float av = ap[l];
    f32x4 v = *(const f32x4*)(vp + (size_t)l*DM);
#pragma unroll
    for (int j = 0; j < 4; ++j) acc[j] += av * v[j];
  }
  *(f32x4*)(part + (size_t)(b*16 + ch)*DM + c4) = acc;
}

// ---- K6: reduce partials -> context; output = context @ Wf + bf (output #1)
__global__ __launch_bounds__(256) void k_out(const float* __restrict__ part, const float* __restrict__ Wf,
                                             const float* __restrict__ bfv, float* __restrict__ out){
  __shared__ float ctx[DM];
  int b = blockIdx.x >> 2, nc = blockIdx.x & 3;
  int t = threadIdx.x;
#pragma unroll
  for (int j = 0; j < 4; ++j){
    int k = j*256 + t;
    float s = 0.f;
#pragma unroll
    for (int c = 0; c < 16; ++c) s += part[(size_t)(b*16 + c)*DM + k];
    ctx[k] = s;
  }
  __syncthreads();
  int n = nc*256 + t;
  float acc = bfv[n];
#pragma unroll 8
  for (int k = 0; k < DM; ++k) acc += ctx[k] * Wf[(size_t)k*DM + n];
  out[(size_t)b*DM + n] = acc;
}

extern "C" void kernel_launch(void* const* d_in, const int* in_sizes, int n_in,
                              void* d_out, int out_size, void* d_ws, size_t ws_size,
                              hipStream_t stream){
  (void)in_sizes; (void)n_in; (void)out_size;
  const float* key   = (const float*)d_in[0];
  const float* value = (const float*)d_in[1];
  const float* query = (const float*)d_in[2];
  const int*   mask  = (const int*)d_in[3];
  const float* Wk    = (const float*)d_in[4];
  const float* bk    = (const float*)d_in[5];
  const float* Wq    = (const float*)d_in[6];
  const float* bq    = (const float*)d_in[7];
  const float* wsc   = (const float*)d_in[8];
  // d_in[9] = b_score: softmax-invariant, unused
  const float* Wf    = (const float*)d_in[10];
  const float* bfv   = (const float*)d_in[11];

  float* out0 = (float*)d_out;
  float* attn = out0 + (size_t)B_ * DM;   // [B,H,1,Lk] region

  char* ws = (char*)d_ws;
  ushort* wkt  = (ushort*)(ws);                                    // 2 MB
  float*  qup  = (float*)(ws + (2u<<20));                          // 128 KB
  float*  scr  = (float*)(ws + (2u<<20) + (128u<<10));             // 4 MB
  float*  part = (float*)(ws + (2u<<20) + (128u<<10) + (4u<<20));  // 2 MB
  const size_t base = (2u<<20) + (128u<<10) + (4u<<20) + (2u<<20); // 8.125 MB
  ushort* keybf = (ushort*)(ws + base);                            // 128 MB (fast path)
  const bool fast = ws_size >= base + ((size_t)B_*LK*DM*sizeof(ushort));

  k_wkt<<<dim3(32, 32), 256, 0, stream>>>(Wk, wkt);
  k_qup<<<128, 256, 0, stream>>>(query, Wq, bq, qup);
  if (fast){
    k_keybf<<<32768, 256, 0, stream>>>(key, keybf);
    k_gemm_fast<<<4096, 256, 0, stream>>>(keybf, wkt, qup, bk, wsc, scr);
  } else {
    k_gemm_scores<<<512, 256, 0, stream>>>(key, wkt, qup, bk, wsc, scr);
  }
  k_softmax<<<512, 256, 0, stream>>>(scr, mask, attn);
  k_ctx<<<512, 256, 0, stream>>>(value, attn, part);
  k_out<<<128, 256, 0, stream>>>(part, Wf, bfv, out0);
}

// Round 4
// 379.228 us; speedup vs baseline: 1.4540x; 1.1496x over previous
//
#include <hip/hip_runtime.h>
#include <hip/hip_bf16.h>

#define B_  32
#define LK  2048
#define DM  1024
#define NH  16

typedef __attribute__((ext_vector_type(8))) short short8;
typedef __attribute__((ext_vector_type(4))) float f32x4;

__device__ __forceinline__ ushort f2bf(float f){
  union { float f; unsigned u; } v; v.f = f;
  unsigned u = v.u;
  u += 0x7fffu + ((u >> 16) & 1u);   // RNE
  return (ushort)(u >> 16);
}

__device__ __forceinline__ short8 pack8(f32x4 a, f32x4 b){
  union { __hip_bfloat162 h[4]; short8 s; } r;
  r.h[0] = __float22bfloat162_rn(make_float2(a[0], a[1]));
  r.h[1] = __float22bfloat162_rn(make_float2(a[2], a[3]));
  r.h[2] = __float22bfloat162_rn(make_float2(b[0], b[1]));
  r.h[3] = __float22bfloat162_rn(make_float2(b[2], b[3]));
  return r.s;
}

__device__ __forceinline__ void gll16(const void* g, void* l){
  __builtin_amdgcn_global_load_lds(
      (__attribute__((address_space(1))) void*)g,
      (__attribute__((address_space(3))) void*)l, 16, 0, 0);
}

#define C2LOG2E 2.8853900817779268f  /* 2*log2(e) */

// ---- K0: merged prepass. blocks 0..1023: Wk->wkt transpose+bf16. 1024..1151: qup GEMV.
__global__ __launch_bounds__(256) void k_pre(const float* __restrict__ Wk, ushort* __restrict__ wkt,
                                             const float* __restrict__ query, const float* __restrict__ Wq,
                                             const float* __restrict__ bq, float* __restrict__ qup){
  __shared__ float smem[1056];
  int bid = blockIdx.x;
  int t = threadIdx.x;
  if (bid < 1024){
    float (*tile)[33] = (float(*)[33])smem;
    int n0 = (bid & 31) * 32, k0 = (bid >> 5) * 32;
    int tx = t & 31, ty = t >> 5;
#pragma unroll
    for (int r = 0; r < 4; ++r)
      tile[ty + 8*r][tx] = Wk[(size_t)(k0 + ty + 8*r) * DM + n0 + tx];
    __syncthreads();
#pragma unroll
    for (int r = 0; r < 4; ++r){
      int n = ty + 8*r;
      wkt[(size_t)(n0 + n) * DM + k0 + tx] = f2bf(tile[tx][n]);
    }
  } else {
    int bb = bid - 1024;
    int b = bb >> 2, nc = bb & 3;
    float* q = smem;
#pragma unroll
    for (int j = 0; j < 4; ++j) q[j*256 + t] = query[(size_t)b*DM + j*256 + t];
    __syncthreads();
    int n = nc*256 + t;
    float acc = bq[n];
#pragma unroll 8
    for (int k = 0; k < DM; ++k) acc += q[k] * Wq[(size_t)k*DM + n];
    qup[(size_t)b*DM + n] = acc;
  }
}

// ---- K2: MFMA GEMM, key f32 read DIRECTLY (no prepass).
// A: reg-staged (8x dwordx4 -> cvt_pk bf16 -> linear 1KB/wave ds_write, T14 issue-early/write-late)
// B: global_load_lds w/ pre-swizzled source. Both LDS images XOR-swizzled: kb ^= (row&7)<<4.
// Grid 4096 = 8 xcd * 64 rbLocal * 8 ct; ct-siblings grouped on one XCD (T1).
__global__ __launch_bounds__(256, 3) void k_gemm(
    const float* __restrict__ key, const ushort* __restrict__ wkt,
    const float* __restrict__ qup, const float* __restrict__ bk,
    const float* __restrict__ wsc, float* __restrict__ scores)
{
  __shared__ ushort ldsA[8192];   // 16 KB, 128 rows x 64 k (swizzled image)
  __shared__ ushort ldsB0[8192];  // 16 KB dbuf half
  __shared__ ushort ldsB1[8192];
  const int tid  = threadIdx.x;
  const int lane = tid & 63;
  const int wid  = tid >> 6;
  const int wr   = wid >> 1, wc = wid & 1;
  const int l15  = lane & 15, l16 = lane >> 4;

  // T1: XCD-grouped decode (hw round-robin: xcd ~ bid&7)
  const int bid = blockIdx.x;
  const int xcd = bid & 7;
  const int j   = bid >> 3;             // 0..511
  const int ct  = j & 7;                // column tile / head pair
  const int rb  = xcd * 64 + (j >> 3);  // row panel 0..511 (8 ct-siblings share rb & xcd)
  const size_t row0 = (size_t)rb * 128;
  const int b  = rb >> 4;
  const int l0 = (rb & 15) * 128;

  // staging lane geometry (shared by A and B): row-in-group = lane>>3, swizzled k8
  const int g8  = lane >> 3;                 // 0..7
  const int sk8 = (lane & 7) ^ g8;           // pre-swizzled k8 source slot
  // B: gll source; rows wid*32 + c*8 + g8
  const ushort* bbase = wkt + (size_t)(ct*128 + wid*32 + g8) * DM + sk8*8;
  // A: reg-stage source; thread covers rows wid*32 + j4*8 + g8, k8=sk8
  const float* akey = key + (row0 + (size_t)(wid*32 + g8)) * DM + sk8*8;

  float qbc[4], wm2[4], wsum = 0.f;
#pragma unroll
  for (int ni = 0; ni < 4; ++ni){
    int n = ct*128 + wc*64 + ni*16 + l15;
    float w = wsc[ni*16 + l15];
    qbc[ni] = (qup[(size_t)b*DM + n] + bk[n]) * C2LOG2E;
    wm2[ni] = -2.f * w;
    wsum   += w;
  }

  f32x4 acc[4][4];
#pragma unroll
  for (int mi = 0; mi < 4; ++mi)
#pragma unroll
    for (int ni = 0; ni < 4; ++ni) acc[mi][ni] = (f32x4){0.f,0.f,0.f,0.f};

  f32x4 a0[4], a1[4];
  // prologue: A(0) loads, B(0) gll, write A(0), barrier
#pragma unroll
  for (int j4 = 0; j4 < 4; ++j4){
    const float* ap = akey + (size_t)j4*8*DM;
    a0[j4] = *(const f32x4*)ap; a1[j4] = *(const f32x4*)(ap + 4);
  }
#pragma unroll
  for (int c = 0; c < 4; ++c)
    gll16(bbase + (size_t)c*8*DM, (char*)ldsB0 + wid*4096 + c*1024);
#pragma unroll
  for (int j4 = 0; j4 < 4; ++j4)
    *(short8*)((char*)ldsA + (wid*4 + j4)*1024 + lane*16) = pack8(a0[j4], a1[j4]);
  __syncthreads();

  const int sw = (l15 & 7) << 4;   // read-side XOR (row&7)<<4

  for (int kt = 0; kt < 16; ++kt){
    const ushort* Bc = (kt & 1) ? ldsB1 : ldsB0;
    char*         Bn = (char*)((kt & 1) ? ldsB0 : ldsB1);
    if (kt < 15){
#pragma unroll
      for (int j4 = 0; j4 < 4; ++j4){
        const float* ap = akey + (size_t)j4*8*DM + (kt+1)*64;
        a0[j4] = *(const f32x4*)ap; a1[j4] = *(const f32x4*)(ap + 4);
      }
#pragma unroll
      for (int c = 0; c < 4; ++c)
        gll16(bbase + (size_t)(kt+1)*64 + (size_t)c*8*DM, Bn + wid*4096 + c*1024);
    }

    short8 af[4][2], bfr[4][2];
#pragma unroll
    for (int mi = 0; mi < 4; ++mi){
      int row = wr*64 + mi*16 + l15;
      af[mi][0] = *(const short8*)((const char*)ldsA + row*128 + ((l16*16) ^ sw));
      af[mi][1] = *(const short8*)((const char*)ldsA + row*128 + ((64 + l16*16) ^ sw));
    }
#pragma unroll
    for (int ni = 0; ni < 4; ++ni){
      int col = wc*64 + ni*16 + l15;
      bfr[ni][0] = *(const short8*)((const char*)Bc + col*128 + ((l16*16) ^ sw));
      bfr[ni][1] = *(const short8*)((const char*)Bc + col*128 + ((64 + l16*16) ^ sw));
    }
#pragma unroll
    for (int kk = 0; kk < 2; ++kk)
#pragma unroll
      for (int mi = 0; mi < 4; ++mi)
#pragma unroll
        for (int ni = 0; ni < 4; ++ni)
          acc[mi][ni] = __builtin_amdgcn_mfma_f32_16x16x32_bf16(af[mi][kk], bfr[ni][kk], acc[mi][ni], 0, 0, 0);

    __syncthreads();                 // readers done with ldsA; vm drained (a-regs + B gll)
    if (kt < 15){
#pragma unroll
      for (int j4 = 0; j4 < 4; ++j4)
        *(short8*)((char*)ldsA + (wid*4 + j4)*1024 + lane*16) = pack8(a0[j4], a1[j4]);
      __syncthreads();               // A(kt+1) visible
    }
  }

  // epilogue: scores = sum_col w*tanh(acc + q + bk), native exp2/rcp form
#pragma unroll
  for (int mi = 0; mi < 4; ++mi){
    f32x4 s = {wsum, wsum, wsum, wsum};
#pragma unroll
    for (int ni = 0; ni < 4; ++ni)
#pragma unroll
      for (int r = 0; r < 4; ++r){
        float a  = fmaf(acc[mi][ni][r], C2LOG2E, qbc[ni]);
        float e  = __builtin_amdgcn_exp2f(a);
        float rc = __builtin_amdgcn_rcpf(e + 1.f);
        s[r] = fmaf(wm2[ni], rc, s[r]);
      }
#pragma unroll
    for (int r = 0; r < 4; ++r){
      float v = s[r];
      v += __shfl_xor(v, 1);
      v += __shfl_xor(v, 2);
      v += __shfl_xor(v, 4);
      v += __shfl_xor(v, 8);
      s[r] = v;
    }
    if (l15 == 0)
      *(f32x4*)(scores + (size_t)(b*NH + ct*2 + wc)*LK + l0 + wr*64 + mi*16 + l16*4) = s;
  }
}

// ---- K3: masked softmax over l -> attn (output #2)
__global__ __launch_bounds__(256) void k_softmax(const float* __restrict__ scores, const int* __restrict__ mask,
                                                 float* __restrict__ attn){
  int bh = blockIdx.x; int b = bh >> 4;
  const float* s = scores + (size_t)bh * LK;
  const int*   m = mask + (size_t)b * LK;
  float*       a = attn + (size_t)bh * LK;
  int t = threadIdx.x;
  __shared__ float red[8];

  float sv[8]; int mv[8];
  float lmax = -1e30f;
#pragma unroll
  for (int j = 0; j < 8; ++j){
    int i = j*256 + t;
    sv[j] = s[i]; mv[j] = m[i];
    if (!mv[j]) lmax = fmaxf(lmax, sv[j]);
  }
#pragma unroll
  for (int off = 32; off >= 1; off >>= 1) lmax = fmaxf(lmax, __shfl_xor(lmax, off));
  if ((t & 63) == 0) red[t >> 6] = lmax;
  __syncthreads();
  lmax = fmaxf(fmaxf(red[0], red[1]), fmaxf(red[2], red[3]));

  float ev[8]; float lsum = 0.f;
#pragma unroll
  for (int j = 0; j < 8; ++j){
    ev[j] = mv[j] ? 0.f : __expf(sv[j] - lmax);
    lsum += ev[j];
  }
#pragma unroll
  for (int off = 32; off >= 1; off >>= 1) lsum += __shfl_xor(lsum, off);
  if ((t & 63) == 0) red[4 + (t >> 6)] = lsum;
  __syncthreads();
  lsum = red[4] + red[5] + red[6] + red[7];
  float inv = 1.f / lsum;
#pragma unroll
  for (int j = 0; j < 8; ++j) a[j*256 + t] = ev[j] * inv;
}

// ---- K4: context partials: part[b,ch,c] = sum_{l in chunk} attn[b,h(c),l] * value[b,l,c]
__global__ __launch_bounds__(256) void k_ctx(const float* __restrict__ value, const float* __restrict__ attn,
                                             float* __restrict__ part){
  int b = blockIdx.x >> 4, ch = blockIdx.x & 15;
  int t = threadIdx.x;
  int c4 = t * 4;
  int head = t >> 4;
  const float* ap = attn + (size_t)(b*NH + head)*LK + ch*128;
  const float* vp = value + ((size_t)b*LK + ch*128)*DM + c4;
  f32x4 acc = {0.f, 0.f, 0.f, 0.f};
#pragma unroll 4
  for (int l = 0; l < 128; ++l){
    float av = ap[l];
    f32x4 v = *(const f32x4*)(vp + (size_t)l*DM);
#pragma unroll
    for (int j = 0; j < 4; ++j) acc[j] += av * v[j];
  }
  *(f32x4*)(part + (size_t)(b*16 + ch)*DM + c4) = acc;
}

// ---- K6: reduce partials -> context; output = context @ Wf + bf (output #1)
__global__ __launch_bounds__(256) void k_out(const float* __restrict__ part, const float* __restrict__ Wf,
                                             const float* __restrict__ bfv, float* __restrict__ out){
  __shared__ float ctx[DM];
  int b = blockIdx.x >> 2, nc = blockIdx.x & 3;
  int t = threadIdx.x;
#pragma unroll
  for (int j = 0; j < 4; ++j){
    int k = j*256 + t;
    float s = 0.f;
#pragma unroll
    for (int c = 0; c < 16; ++c) s += part[(size_t)(b*16 + c)*DM + k];
    ctx[k] = s;
  }
  __syncthreads();
  int n = nc*256 + t;
  float acc = bfv[n];
#pragma unroll 8
  for (int k = 0; k < DM; ++k) acc += ctx[k] * Wf[(size_t)k*DM + n];
  out[(size_t)b*DM + n] = acc;
}

extern "C" void kernel_launch(void* const* d_in, const int* in_sizes, int n_in,
                              void* d_out, int out_size, void* d_ws, size_t ws_size,
                              hipStream_t stream){
  (void)in_sizes; (void)n_in; (void)out_size; (void)ws_size;
  const float* key   = (const float*)d_in[0];
  const float* value = (const float*)d_in[1];
  const float* query = (const float*)d_in[2];
  const int*   mask  = (const int*)d_in[3];
  const float* Wk    = (const float*)d_in[4];
  const float* bk    = (const float*)d_in[5];
  const float* Wq    = (const float*)d_in[6];
  const float* bq    = (const float*)d_in[7];
  const float* wsc   = (const float*)d_in[8];
  // d_in[9] = b_score: softmax-invariant, unused
  const float* Wf    = (const float*)d_in[10];
  const float* bfv   = (const float*)d_in[11];

  float* out0 = (float*)d_out;
  float* attn = out0 + (size_t)B_ * DM;   // [B,H,1,Lk] region

  char* ws = (char*)d_ws;
  ushort* wkt  = (ushort*)(ws);                                    // 2 MB
  float*  qup  = (float*)(ws + (2u<<20));                          // 128 KB
  float*  scr  = (float*)(ws + (2u<<20) + (128u<<10));             // 4 MB
  float*  part = (float*)(ws + (2u<<20) + (128u<<10) + (4u<<20));  // 2 MB

  k_pre<<<1152, 256, 0, stream>>>(Wk, wkt, query, Wq, bq, qup);
  k_gemm<<<4096, 256, 0, stream>>>(key, wkt, qup, bk, wsc, scr);
  k_softmax<<<512, 256, 0, stream>>>(scr, mask, attn);
  k_ctx<<<512, 256, 0, stream>>>(value, attn, part);
  k_out<<<128, 256, 0, stream>>>(part, Wf, bfv, out0);
}